// Round 13
// baseline (256.586 us; speedup 1.0000x reference)
//
#include <hip/hip_runtime.h>
#include <cstdint>

#define BATCH 4
#define CPD 64
#define RES 64
#define NS 131072
#define NF 512
#define FS 2048
#define HID 16

typedef _Float16 __attribute__((ext_vector_type(8))) f16x8;
typedef float __attribute__((ext_vector_type(16))) f32x16;

typedef union { uint4 u; f16x8 v; } Frag;

// ---------------------------------------------------------------------------
// K1: damping + sequential scan (unchanged)
// ---------------------------------------------------------------------------
__global__ __launch_bounds__(256) void k_scan(const float* __restrict__ forces,
                                              const float* __restrict__ dmod,
                                              const float* __restrict__ dparam,
                                              float* __restrict__ damped_t) {
  __shared__ float f_lds[64][129];
  __shared__ float d_lds[64][129];
  const int b = blockIdx.x;
  const int tid = threadIdx.x;
  float dbase = 0.f, carry = 0.f;
  if (tid < 64) {
    float dp = dparam[tid];
    dbase = 0.5f + (0.9999f - 0.5f) / (1.f + expf(-dp));
  }
  for (int ch = 0; ch < 4; ++ch) {
    const int t0 = ch * 128;
    __syncthreads();
    for (int idx = tid; idx < 64 * 128; idx += 256) {
      int c = idx >> 7, tl = idx & 127;
      f_lds[c][tl] = forces[(b * CPD + c) * NF + t0 + tl];
      d_lds[c][tl] = dmod[(b * CPD + c) * NF + t0 + tl];
    }
    __syncthreads();
    if (tid < 64) {
      const int c = tid;
      for (int tl = 0; tl < 128; ++tl) {
        float d = dbase - fabsf(d_lds[c][tl]);
        d = fminf(fmaxf(d, 0.f), 1.f);
        float f = f_lds[c][tl];
        float out = (ch == 0 && tl == 0) ? f : (f + carry) * d;
        carry = out;
        damped_t[(b * NF + t0 + tl) * CPD + c] = out;
      }
    }
  }
}

// ---------------------------------------------------------------------------
// K2: hypernetwork + routing einsum + to_ctrl (unchanged)
// ---------------------------------------------------------------------------
__global__ __launch_bounds__(256) void k_hyper(const float* __restrict__ damped_t,
                                               const float* __restrict__ routing,
                                               const float* __restrict__ W1,
                                               const float* __restrict__ b1,
                                               const float* __restrict__ W2,
                                               const float* __restrict__ b2,
                                               const float* __restrict__ to_control,
                                               float* __restrict__ routed,
                                               float* __restrict__ to_ctrl) {
  __shared__ float xs[4][64];
  __shared__ float hs[4][16];
  __shared__ float rs[4][64];
  const int blk = blockIdx.x;
  const int b = blk >> 7;
  const int t0 = (blk & 127) * 4;
  const int lt = threadIdx.x >> 6;
  const int d = threadIdx.x & 63;
  const int t = t0 + lt;

  xs[lt][d] = damped_t[(b * NF + t) * CPD + d];
  __syncthreads();
  if (d < HID) {
    float a = b1[d];
    for (int c = 0; c < CPD; ++c) a = fmaf(xs[lt][c], W1[c * HID + d], a);
    hs[lt][d] = a > 0.f ? a : 0.2f * a;
  }
  __syncthreads();
  float hreg[HID];
#pragma unroll
  for (int j = 0; j < HID; ++j) hreg[j] = hs[lt][j];

  float acc = 0.f;
  for (int c = 0; c < CPD; ++c) {
    float w = routing[c * RES + d] + b2[c * RES + d];
    const float* w2p = W2 + c * RES + d;
#pragma unroll
    for (int j = 0; j < HID; ++j) w = fmaf(hreg[j], w2p[j * (CPD * RES)], w);
    acc = fmaf(xs[lt][c], w, acc);
  }
  routed[(b * RES + d) * NF + t] = acc;
  rs[lt][d] = acc;
  __syncthreads();
  float tc = 0.f;
  for (int q = 0; q < RES; ++q) tc = fmaf(rs[lt][q], to_control[q * CPD + d], tc);
  to_ctrl[(b * CPD + d) * NF + t] = tc;
}

// ---------------------------------------------------------------------------
// K-zero: zero the atomic boundary strips (every launch -> replay safe)
// ---------------------------------------------------------------------------
__global__ __launch_bounds__(256) void k_zero(float* __restrict__ reso) {
  const int chan = blockIdx.x;
  const size_t base = (size_t)chan * NS;
  for (int i = threadIdx.x; i < 8192; i += 256) {
    int y;
    if (i < 32) y = i;
    else if (i < 32 + 7168) {
      int s = 1 + ((i - 32) >> 10);
      y = 16384 * s - 992 + ((i - 32) & 1023);
    } else {
      y = 130080 + (i - 7200);
    }
    reso[base + y] = 0.f;
  }
}

// ---------------------------------------------------------------------------
// Tiling constants
// ---------------------------------------------------------------------------
#define SPAN 16384
#define ER_GRAN 2312
#define FC_COPIES 8
#define FC_STRIDE 267
#define FGL_DW (FC_COPIES * FC_STRIDE * 4)   // 8544 dwords per r
#define SMEM_BYTES (ER_GRAN * 16 + FC_COPIES * FC_STRIDE * 16)  // 71168 B

// ---------------------------------------------------------------------------
// K-filter: per-r 8-shift f16 tap-pair table (unchanged)
// ---------------------------------------------------------------------------
__global__ __launch_bounds__(256) void k_filter(const float* __restrict__ filters,
                                                unsigned* __restrict__ fgl) {
  const int r = blockIdx.x;
  const float* fr = filters + r * FS;
  unsigned* dst = fgl + r * FGL_DW;
  for (int idx = threadIdx.x; idx < FGL_DW; idx += 256) {
    int c = idx / (FC_STRIDE * 4);
    int d = idx - c * (FC_STRIDE * 4);
    int t0 = 2 * d + c - 32;
    float f0 = (t0 >= 0 && t0 < FS) ? fr[t0] : 0.f;
    float f1 = (t0 + 1 >= 0 && t0 + 1 < FS) ? fr[t0 + 1] : 0.f;
    union { _Float16 h[2]; unsigned u; } P;
    P.h[0] = (_Float16)f0;
    P.h[1] = (_Float16)f1;
    dst[idx] = P.u;
  }
}

// ---------------------------------------------------------------------------
// K3: block-Hankel GEMM conv, r13: 4 segs per block, filter staged ONCE.
// Grid 512 (= 2 blocks/CU): block = (b, r, half); loops segs 4*half..4*half+3.
// Per seg: stage energy (r12 branchless/unrolled path) -> compute -> epilogue.
// Filter-table LDS writes drop 8x -> per-CU LDS ops -25% (the binding pipe).
// Epilogue scratch lives in the energy region (rewritten next seg); loop-head
// barrier orders scr reads before the overwrite.
// ---------------------------------------------------------------------------
__global__ __launch_bounds__(512, 4) void k_conv(const float* __restrict__ routed,
                                                 const float* __restrict__ noise,
                                                 float* __restrict__ outp,
                                                 const unsigned* __restrict__ fgl) {
  __shared__ __align__(16) unsigned char smem[SMEM_BYTES];
  unsigned char* erb = smem;
  unsigned char* fcb = smem + ER_GRAN * 16;

  const int tid = threadIdx.x;
  const int half = blockIdx.x & 1;
  const int r = (blockIdx.x >> 1) & 63;
  const int b = blockIdx.x >> 7;
  const int chan = b * RES + r;
  const float* rp = routed + chan * NF;
  const float* npz = noise + (size_t)chan * NS;
  float* cbase = outp + (size_t)chan * NS;
  const float scale = 1.f / 1024.f;

  // ---- filter table: staged ONCE per block ----
  {
    const uint4* fg = (const uint4*)(fgl + r * FGL_DW);
    uint4* fc4 = (uint4*)fcb;
#pragma unroll
    for (int k = 0; k < 4; ++k) fc4[tid + 512 * k] = fg[tid + 512 * k];
    if (tid < FGL_DW / 4 - 2048) fc4[2048 + tid] = fg[2048 + tid];
  }

  const int w = tid >> 6;
  const int l = tid & 63;
  const int row = l & 31;
  const int h = l >> 5;

  const int gaA = 2048 - 256 * w + 4 * row + h;
  const int gaB = gaA - 128;
  const int qcb = (row & 7) * FC_STRIDE + (row >> 3) + h;

  for (int s4 = 0; s4 < 4; ++s4) {
    const int seg = half * 4 + s4;
    const int NB = seg * SPAN;
    const int E0 = NB + SPAN + 32;      // er[x] = e[E0-x]*1024

    __syncthreads();   // prior epilogue's scr reads done before overwrite

    // ---- stage energy: branchless, unrolled ----
    {
      const int n0base = E0 - 18431;
#define STAGEG(T_)                                                            \
      {                                                                       \
        const int t_ = (T_);                                                  \
        const int n0 = n0base + 8 * t_;                                       \
        const int g = 2303 - t_;                                              \
        const int nc = min(max(n0, 0), NS - 8);                               \
        const float4 na = *(const float4*)(npz + nc);                         \
        const float4 nb = *(const float4*)(npz + nc + 4);                     \
        float pos0 = fminf(fmaxf(fmaf((float)n0 + 0.5f, 1.f / 256.f, -0.5f), 0.f), 511.f); \
        float pos7 = fminf(fmaxf(fmaf((float)n0 + 7.5f, 1.f / 256.f, -0.5f), 0.f), 511.f); \
        const int ia = min((int)pos0, 510);                                   \
        const int ib = min((int)pos7, 510);                                   \
        const float c0 = rp[ia], c1 = rp[ia + 1];                             \
        const float c2 = rp[ib], c3 = rp[ib + 1];                             \
        const float iaf = (float)ia;                                          \
        const float nv[8] = {na.x, na.y, na.z, na.w, nb.x, nb.y, nb.z, nb.w}; \
        union { _Float16 hh[8]; uint4 u; } O;                                 \
        _Pragma("unroll")                                                     \
        for (int k = 0; k < 8; ++k) {                                         \
          const int n = n0 + k;                                               \
          float pos = fminf(fmaxf(fmaf((float)n + 0.5f, 1.f / 256.f, -0.5f), 0.f), 511.f); \
          float i0f = fminf(floorf(pos), 510.f);                              \
          float fr = pos - i0f;                                               \
          bool sel = i0f > iaf;                                               \
          float lo = sel ? c2 : c0;                                           \
          float hi = sel ? c3 : c1;                                           \
          float u = fmaf(fr, hi - lo, lo);                                    \
          float e = (n >= 0 && n < NS) ? u * nv[k] * 1024.f : 0.f;            \
          O.hh[7 - k] = (_Float16)e;                                          \
        }                                                                     \
        const int gs = g ^ ((g >> 3) & 7);                                    \
        *(uint4*)(erb + (gs << 4)) = O.u;                                     \
      }
#pragma unroll
      for (int k = 0; k < 4; ++k) STAGEG(tid + 512 * k)
      if (tid < 256) STAGEG(2048 + tid)
#undef STAGEG
    }
    __syncthreads();

    f32x16 p00, p01, p10, p11;
#pragma unroll
    for (int i = 0; i < 16; ++i) { p00[i] = 0.f; p01[i] = 0.f; p10[i] = 0.f; p11[i] = 0.f; }

#define LOADA(DST, GB, SG_)                                                   \
    { int g = (GB) + 2 * (SG_); int ab = (g ^ ((g >> 3) & 7)) << 4;           \
      DST.u = *(const uint4*)(erb + ab); }
#define LOADBF(DST, SG_, J_)                                                  \
    { int gb = qcb + 2 * (SG_) + 128 * (J_);                                  \
      DST.u = *(const uint4*)(fcb + (gb << 4)); }

    for (int sg = 0; sg < 2; ++sg) {
      Frag B0, A0, A1;
      LOADBF(B0, sg, 0)
      LOADA(A0, gaA, sg) LOADA(A1, gaB, sg)
      p00 = __builtin_amdgcn_mfma_f32_32x32x16_f16(A0.v, B0.v, p00, 0, 0, 0);
      p10 = __builtin_amdgcn_mfma_f32_32x32x16_f16(A1.v, B0.v, p10, 0, 0, 0);
    }
    for (int sg = 2; sg < 66; ++sg) {
      Frag B0, B1, A0, A1;
      LOADBF(B0, sg, 0) LOADBF(B1, sg, 1)
      LOADA(A0, gaA, sg) LOADA(A1, gaB, sg)
      p00 = __builtin_amdgcn_mfma_f32_32x32x16_f16(A0.v, B0.v, p00, 0, 0, 0);
      p01 = __builtin_amdgcn_mfma_f32_32x32x16_f16(A0.v, B1.v, p01, 0, 0, 0);
      p10 = __builtin_amdgcn_mfma_f32_32x32x16_f16(A1.v, B0.v, p10, 0, 0, 0);
      p11 = __builtin_amdgcn_mfma_f32_32x32x16_f16(A1.v, B1.v, p11, 0, 0, 0);
    }

    if (seg == 7 && w == 7) {           // global-top orphan phase-0 half
      f32x16 ax;
#pragma unroll
      for (int i = 0; i < 16; ++i) ax[i] = 0.f;
      const int ge = 4 * row + h;
      for (int sg = 0; sg < 66; ++sg) {
        Frag Bx, Ax;
        LOADBF(Bx, sg, 0)
        LOADA(Ax, ge, sg)
        ax = __builtin_amdgcn_mfma_f32_32x32x16_f16(Ax.v, Bx.v, ax, 0, 0, 0);
      }
#pragma unroll
      for (int i = 0; i < 16; ++i) p11[i] += ax[i];
    }
#undef LOADA
#undef LOADBF

    // ---- epilogue for this seg ----
    {
      float* po = cbase + NB + 1024 * (2 * w + 1);
#pragma unroll
      for (int rg = 0; rg < 16; ++rg) {
        int crow = (rg & 3) + 8 * (rg >> 2) + 4 * h;
        po[row - 32 * crow] = (p10[rg] + p01[rg]) * scale;
      }
    }

    __syncthreads();                     // all compute reads of erb done
    float* scr = (float*)smem;           // reuse energy region (32 KB)
#pragma unroll
    for (int rg = 0; rg < 16; ++rg) scr[w * 1024 + rg * 64 + l] = p11[rg];
    __syncthreads();

    if (w >= 1) {
      float* po = cbase + NB + 1024 * (2 * w);
#pragma unroll
      for (int rg = 0; rg < 16; ++rg) {
        int crow = (rg & 3) + 8 * (rg >> 2) + 4 * h;
        po[row - 32 * crow] = (p00[rg] + scr[(w - 1) * 1024 + rg * 64 + l]) * scale;
      }
    } else {
#pragma unroll
      for (int rg = 0; rg < 16; ++rg) {
        int crow = (rg & 3) + 8 * (rg >> 2) + 4 * h;
        int y = NB + row - 32 * crow;
        if (y >= 0) atomicAdd(cbase + y, p00[rg] * scale);
      }
    }
    if (w == 7) {
#pragma unroll
      for (int rg = 0; rg < 16; ++rg) {
        int crow = (rg & 3) + 8 * (rg >> 2) + 4 * h;
        int y = NB + SPAN + row - 32 * crow;
        if (y < NS) atomicAdd(cbase + y, p11[rg] * scale);
      }
    }
  }
}

// ---------------------------------------------------------------------------
extern "C" void kernel_launch(void* const* d_in, const int* in_sizes, int n_in,
                              void* d_out, int out_size, void* d_ws, size_t ws_size,
                              hipStream_t stream) {
  const float* forces     = (const float*)d_in[0];
  const float* dmod       = (const float*)d_in[1];
  const float* noise      = (const float*)d_in[2];
  const float* dparam     = (const float*)d_in[3];
  const float* routing    = (const float*)d_in[4];
  const float* W1         = (const float*)d_in[5];
  const float* b1         = (const float*)d_in[6];
  const float* W2         = (const float*)d_in[7];
  const float* b2         = (const float*)d_in[8];
  const float* filters    = (const float*)d_in[9];
  const float* to_control = (const float*)d_in[10];

  float* out = (float*)d_out;
  float* to_ctrl = out;                                  // (B,CPD,NF)
  float* reso = out + BATCH * CPD * NF;                  // (B,RES,NS)

  char* ws = (char*)d_ws;
  float* damped_t = (float*)ws;                          // 512 KB
  float* routed = (float*)(ws + (512 << 10));            // 512 KB
  unsigned* fgl = (unsigned*)(ws + (1 << 20));           // 2.19 MB

  k_scan<<<BATCH, 256, 0, stream>>>(forces, dmod, dparam, damped_t);
  k_hyper<<<BATCH * NF / 4, 256, 0, stream>>>(damped_t, routing, W1, b1, W2, b2,
                                              to_control, routed, to_ctrl);
  k_filter<<<RES, 256, 0, stream>>>(filters, fgl);
  k_zero<<<BATCH * RES, 256, 0, stream>>>(reso);
  k_conv<<<BATCH * RES * 2, 512, 0, stream>>>(routed, noise, reso, fgl);
}

// Round 14
// 210.375 us; speedup vs baseline: 1.2197x; 1.2197x over previous
//
#include <hip/hip_runtime.h>
#include <cstdint>

#define BATCH 4
#define CPD 64
#define RES 64
#define NS 131072
#define NF 512
#define FS 2048
#define HID 16

typedef _Float16 __attribute__((ext_vector_type(8))) f16x8;
typedef float __attribute__((ext_vector_type(16))) f32x16;

typedef union { uint4 u; f16x8 v; } Frag;

// ---------------------------------------------------------------------------
// Tiling constants
// ---------------------------------------------------------------------------
#define SPAN 16384
#define ER_GRAN 2312
#define FC_COPIES 8
#define FC_STRIDE 267
#define FGL_DW (FC_COPIES * FC_STRIDE * 4)   // 8544 dwords per r
#define SMEM_BYTES (ER_GRAN * 16 + FC_COPIES * FC_STRIDE * 16)  // 71168 B

// ---------------------------------------------------------------------------
// K-pre: merged {scan | filter-table | zero-strips} — mutually independent
// roles dispatched by blockIdx. Saves 2 kernel launches.
//   blocks [0,4):    damping scan for batch b
//   blocks [4,68):   8-shift f16 filter table for r = blk-4
//   blocks [68,324): zero atomic strips for chan = blk-68
// ---------------------------------------------------------------------------
__global__ __launch_bounds__(256) void k_pre(const float* __restrict__ forces,
                                             const float* __restrict__ dmod,
                                             const float* __restrict__ dparam,
                                             float* __restrict__ damped_t,
                                             const float* __restrict__ filters,
                                             unsigned* __restrict__ fgl,
                                             float* __restrict__ reso) {
  const int blk = blockIdx.x;
  const int tid = threadIdx.x;

  if (blk < 4) {
    // ---- damping + sequential scan ----
    __shared__ float f_lds[64][129];
    __shared__ float d_lds[64][129];
    const int b = blk;
    float dbase = 0.f, carry = 0.f;
    if (tid < 64) {
      float dp = dparam[tid];
      dbase = 0.5f + (0.9999f - 0.5f) / (1.f + expf(-dp));
    }
    for (int ch = 0; ch < 4; ++ch) {
      const int t0 = ch * 128;
      __syncthreads();
      for (int idx = tid; idx < 64 * 128; idx += 256) {
        int c = idx >> 7, tl = idx & 127;
        f_lds[c][tl] = forces[(b * CPD + c) * NF + t0 + tl];
        d_lds[c][tl] = dmod[(b * CPD + c) * NF + t0 + tl];
      }
      __syncthreads();
      if (tid < 64) {
        const int c = tid;
        for (int tl = 0; tl < 128; ++tl) {
          float d = dbase - fabsf(d_lds[c][tl]);
          d = fminf(fmaxf(d, 0.f), 1.f);
          float f = f_lds[c][tl];
          float out = (ch == 0 && tl == 0) ? f : (f + carry) * d;
          carry = out;
          damped_t[(b * NF + t0 + tl) * CPD + c] = out;
        }
      }
    }
  } else if (blk < 68) {
    // ---- filter table ----
    const int r = blk - 4;
    const float* fr = filters + r * FS;
    unsigned* dst = fgl + r * FGL_DW;
    for (int idx = tid; idx < FGL_DW; idx += 256) {
      int c = idx / (FC_STRIDE * 4);
      int d = idx - c * (FC_STRIDE * 4);
      int t0 = 2 * d + c - 32;
      float f0 = (t0 >= 0 && t0 < FS) ? fr[t0] : 0.f;
      float f1 = (t0 + 1 >= 0 && t0 + 1 < FS) ? fr[t0 + 1] : 0.f;
      union { _Float16 h[2]; unsigned u; } P;
      P.h[0] = (_Float16)f0;
      P.h[1] = (_Float16)f1;
      dst[idx] = P.u;
    }
  } else {
    // ---- zero atomic boundary strips ----
    const int chan = blk - 68;
    const size_t base = (size_t)chan * NS;
    for (int i = tid; i < 8192; i += 256) {
      int y;
      if (i < 32) y = i;
      else if (i < 32 + 7168) {
        int s = 1 + ((i - 32) >> 10);
        y = 16384 * s - 992 + ((i - 32) & 1023);
      } else {
        y = 130080 + (i - 7200);
      }
      reso[base + y] = 0.f;
    }
  }
}

// ---------------------------------------------------------------------------
// K2: hypernetwork + routing einsum + to_ctrl (unchanged)
// ---------------------------------------------------------------------------
__global__ __launch_bounds__(256) void k_hyper(const float* __restrict__ damped_t,
                                               const float* __restrict__ routing,
                                               const float* __restrict__ W1,
                                               const float* __restrict__ b1,
                                               const float* __restrict__ W2,
                                               const float* __restrict__ b2,
                                               const float* __restrict__ to_control,
                                               float* __restrict__ routed,
                                               float* __restrict__ to_ctrl) {
  __shared__ float xs[4][64];
  __shared__ float hs[4][16];
  __shared__ float rs[4][64];
  const int blk = blockIdx.x;
  const int b = blk >> 7;
  const int t0 = (blk & 127) * 4;
  const int lt = threadIdx.x >> 6;
  const int d = threadIdx.x & 63;
  const int t = t0 + lt;

  xs[lt][d] = damped_t[(b * NF + t) * CPD + d];
  __syncthreads();
  if (d < HID) {
    float a = b1[d];
    for (int c = 0; c < CPD; ++c) a = fmaf(xs[lt][c], W1[c * HID + d], a);
    hs[lt][d] = a > 0.f ? a : 0.2f * a;
  }
  __syncthreads();
  float hreg[HID];
#pragma unroll
  for (int j = 0; j < HID; ++j) hreg[j] = hs[lt][j];

  float acc = 0.f;
  for (int c = 0; c < CPD; ++c) {
    float w = routing[c * RES + d] + b2[c * RES + d];
    const float* w2p = W2 + c * RES + d;
#pragma unroll
    for (int j = 0; j < HID; ++j) w = fmaf(hreg[j], w2p[j * (CPD * RES)], w);
    acc = fmaf(xs[lt][c], w, acc);
  }
  routed[(b * RES + d) * NF + t] = acc;
  rs[lt][d] = acc;
  __syncthreads();
  float tc = 0.f;
  for (int q = 0; q < RES; ++q) tc = fmaf(rs[lt][q], to_control[q * CPD + d], tc);
  to_ctrl[(b * CPD + d) * NF + t] = tc;
}

// ---------------------------------------------------------------------------
// K3: block-Hankel GEMM conv — r12 form, binary-identical structure.
// ---------------------------------------------------------------------------
__global__ __launch_bounds__(512, 4) void k_conv(const float* __restrict__ routed,
                                                 const float* __restrict__ noise,
                                                 float* __restrict__ outp,
                                                 const unsigned* __restrict__ fgl) {
  __shared__ __align__(16) unsigned char smem[SMEM_BYTES];
  unsigned char* erb = smem;
  unsigned char* fcb = smem + ER_GRAN * 16;

  const int tid = threadIdx.x;
  const int seg = blockIdx.x & 7;
  const int r = (blockIdx.x >> 3) & 63;
  const int b = blockIdx.x >> 9;
  const int NB = seg * SPAN;
  const int E0 = NB + SPAN + 32;      // er[x] = e[E0-x]*1024
  const int chan = b * RES + r;

  // ---- staging B: filter table copy (unrolled) ----
  {
    const uint4* fg = (const uint4*)(fgl + r * FGL_DW);
    uint4* fc4 = (uint4*)fcb;
#pragma unroll
    for (int k = 0; k < 4; ++k) fc4[tid + 512 * k] = fg[tid + 512 * k];
    if (tid < FGL_DW / 4 - 2048) fc4[2048 + tid] = fg[2048 + tid];
  }

  // ---- staging A: fused energy, branchless, unrolled ----
  {
    const float* rp = routed + chan * NF;
    const float* npz = noise + (size_t)chan * NS;
    const int n0base = E0 - 18431;

#define STAGEG(T_)                                                            \
    {                                                                         \
      const int t_ = (T_);                                                    \
      const int n0 = n0base + 8 * t_;                                         \
      const int g = 2303 - t_;                                                \
      const int nc = min(max(n0, 0), NS - 8);                                 \
      const float4 na = *(const float4*)(npz + nc);                           \
      const float4 nb = *(const float4*)(npz + nc + 4);                       \
      float pos0 = fminf(fmaxf(fmaf((float)n0 + 0.5f, 1.f / 256.f, -0.5f), 0.f), 511.f); \
      float pos7 = fminf(fmaxf(fmaf((float)n0 + 7.5f, 1.f / 256.f, -0.5f), 0.f), 511.f); \
      const int ia = min((int)pos0, 510);                                     \
      const int ib = min((int)pos7, 510);                                     \
      const float c0 = rp[ia], c1 = rp[ia + 1];                               \
      const float c2 = rp[ib], c3 = rp[ib + 1];                               \
      const float iaf = (float)ia;                                            \
      const float nv[8] = {na.x, na.y, na.z, na.w, nb.x, nb.y, nb.z, nb.w};   \
      union { _Float16 h[8]; uint4 u; } O;                                    \
      _Pragma("unroll")                                                       \
      for (int k = 0; k < 8; ++k) {                                           \
        const int n = n0 + k;                                                 \
        float pos = fminf(fmaxf(fmaf((float)n + 0.5f, 1.f / 256.f, -0.5f), 0.f), 511.f); \
        float i0f = fminf(floorf(pos), 510.f);                                \
        float fr = pos - i0f;                                                 \
        bool sel = i0f > iaf;                                                 \
        float lo = sel ? c2 : c0;                                             \
        float hi = sel ? c3 : c1;                                             \
        float u = fmaf(fr, hi - lo, lo);                                      \
        float e = (n >= 0 && n < NS) ? u * nv[k] * 1024.f : 0.f;              \
        O.h[7 - k] = (_Float16)e;                                             \
      }                                                                       \
      const int gs = g ^ ((g >> 3) & 7);                                      \
      *(uint4*)(erb + (gs << 4)) = O.u;                                       \
    }

#pragma unroll
    for (int k = 0; k < 4; ++k) STAGEG(tid + 512 * k)
    if (tid < 256) STAGEG(2048 + tid)
#undef STAGEG
  }
  __syncthreads();

  const int w = tid >> 6;
  const int l = tid & 63;
  const int row = l & 31;
  const int h = l >> 5;

  const int gaA = 2048 - 256 * w + 4 * row + h;
  const int gaB = gaA - 128;
  const int qcb = (row & 7) * FC_STRIDE + (row >> 3) + h;

  f32x16 p00, p01, p10, p11;
#pragma unroll
  for (int i = 0; i < 16; ++i) { p00[i] = 0.f; p01[i] = 0.f; p10[i] = 0.f; p11[i] = 0.f; }

#define LOADA(DST, GB, SG_)                                                   \
  { int g = (GB) + 2 * (SG_); int ab = (g ^ ((g >> 3) & 7)) << 4;             \
    DST.u = *(const uint4*)(erb + ab); }
#define LOADBF(DST, SG_, J_)                                                  \
  { int gb = qcb + 2 * (SG_) + 128 * (J_);                                    \
    DST.u = *(const uint4*)(fcb + (gb << 4)); }

  for (int sg = 0; sg < 2; ++sg) {
    Frag B0, A0, A1;
    LOADBF(B0, sg, 0)
    LOADA(A0, gaA, sg) LOADA(A1, gaB, sg)
    p00 = __builtin_amdgcn_mfma_f32_32x32x16_f16(A0.v, B0.v, p00, 0, 0, 0);
    p10 = __builtin_amdgcn_mfma_f32_32x32x16_f16(A1.v, B0.v, p10, 0, 0, 0);
  }
  for (int sg = 2; sg < 66; ++sg) {
    Frag B0, B1, A0, A1;
    LOADBF(B0, sg, 0) LOADBF(B1, sg, 1)
    LOADA(A0, gaA, sg) LOADA(A1, gaB, sg)
    p00 = __builtin_amdgcn_mfma_f32_32x32x16_f16(A0.v, B0.v, p00, 0, 0, 0);
    p01 = __builtin_amdgcn_mfma_f32_32x32x16_f16(A0.v, B1.v, p01, 0, 0, 0);
    p10 = __builtin_amdgcn_mfma_f32_32x32x16_f16(A1.v, B0.v, p10, 0, 0, 0);
    p11 = __builtin_amdgcn_mfma_f32_32x32x16_f16(A1.v, B1.v, p11, 0, 0, 0);
  }

  if (seg == 7 && w == 7) {           // global-top orphan phase-0 half
    f32x16 ax;
#pragma unroll
    for (int i = 0; i < 16; ++i) ax[i] = 0.f;
    const int ge = 4 * row + h;
    for (int sg = 0; sg < 66; ++sg) {
      Frag Bx, Ax;
      LOADBF(Bx, sg, 0)
      LOADA(Ax, ge, sg)
      ax = __builtin_amdgcn_mfma_f32_32x32x16_f16(Ax.v, Bx.v, ax, 0, 0, 0);
    }
#pragma unroll
    for (int i = 0; i < 16; ++i) p11[i] += ax[i];
  }
#undef LOADA
#undef LOADBF

  float* cbase = outp + (size_t)chan * NS;
  const float scale = 1.f / 1024.f;

  {
    float* po = cbase + NB + 1024 * (2 * w + 1);
#pragma unroll
    for (int rg = 0; rg < 16; ++rg) {
      int crow = (rg & 3) + 8 * (rg >> 2) + 4 * h;
      po[row - 32 * crow] = (p10[rg] + p01[rg]) * scale;
    }
  }

  __syncthreads();
  float* scr = (float*)smem;
#pragma unroll
  for (int rg = 0; rg < 16; ++rg) scr[w * 1024 + rg * 64 + l] = p11[rg];
  __syncthreads();

  if (w >= 1) {
    float* po = cbase + NB + 1024 * (2 * w);
#pragma unroll
    for (int rg = 0; rg < 16; ++rg) {
      int crow = (rg & 3) + 8 * (rg >> 2) + 4 * h;
      po[row - 32 * crow] = (p00[rg] + scr[(w - 1) * 1024 + rg * 64 + l]) * scale;
    }
  } else {
#pragma unroll
    for (int rg = 0; rg < 16; ++rg) {
      int crow = (rg & 3) + 8 * (rg >> 2) + 4 * h;
      int y = NB + row - 32 * crow;
      if (y >= 0) atomicAdd(cbase + y, p00[rg] * scale);
    }
  }
  if (w == 7) {
#pragma unroll
    for (int rg = 0; rg < 16; ++rg) {
      int crow = (rg & 3) + 8 * (rg >> 2) + 4 * h;
      int y = NB + SPAN + row - 32 * crow;
      if (y < NS) atomicAdd(cbase + y, p11[rg] * scale);
    }
  }
}

// ---------------------------------------------------------------------------
extern "C" void kernel_launch(void* const* d_in, const int* in_sizes, int n_in,
                              void* d_out, int out_size, void* d_ws, size_t ws_size,
                              hipStream_t stream) {
  const float* forces     = (const float*)d_in[0];
  const float* dmod       = (const float*)d_in[1];
  const float* noise      = (const float*)d_in[2];
  const float* dparam     = (const float*)d_in[3];
  const float* routing    = (const float*)d_in[4];
  const float* W1         = (const float*)d_in[5];
  const float* b1         = (const float*)d_in[6];
  const float* W2         = (const float*)d_in[7];
  const float* b2         = (const float*)d_in[8];
  const float* filters    = (const float*)d_in[9];
  const float* to_control = (const float*)d_in[10];

  float* out = (float*)d_out;
  float* to_ctrl = out;                                  // (B,CPD,NF)
  float* reso = out + BATCH * CPD * NF;                  // (B,RES,NS)

  char* ws = (char*)d_ws;
  float* damped_t = (float*)ws;                          // 512 KB
  float* routed = (float*)(ws + (512 << 10));            // 512 KB
  unsigned* fgl = (unsigned*)(ws + (1 << 20));           // 2.19 MB

  k_pre<<<4 + RES + BATCH * RES, 256, 0, stream>>>(forces, dmod, dparam, damped_t,
                                                   filters, fgl, reso);
  k_hyper<<<BATCH * NF / 4, 256, 0, stream>>>(damped_t, routing, W1, b1, W2, b2,
                                              to_control, routed, to_ctrl);
  k_conv<<<BATCH * RES * (NS / SPAN), 512, 0, stream>>>(routed, noise, reso, fgl);
}

// Round 15
// 208.409 us; speedup vs baseline: 1.2312x; 1.0094x over previous
//
#include <hip/hip_runtime.h>
#include <cstdint>

#define BATCH 4
#define CPD 64
#define RES 64
#define NS 131072
#define NF 512
#define FS 2048
#define HID 16

typedef _Float16 __attribute__((ext_vector_type(8))) f16x8;
typedef float __attribute__((ext_vector_type(16))) f32x16;

typedef union { uint4 u; f16x8 v; } Frag;

// ---------------------------------------------------------------------------
// Tiling constants
// ---------------------------------------------------------------------------
#define SPAN 16384
#define ER_GRAN 2312
#define FC_COPIES 8
#define FC_STRIDE 267
#define FGL_DW (FC_COPIES * FC_STRIDE * 4)   // 8544 dwords per r
#define SMEM_BYTES (ER_GRAN * 16 + FC_COPIES * FC_STRIDE * 16)  // 71168 B

// ---------------------------------------------------------------------------
// K-pre: merged {scan | filter-table | zero-strips} (r14 form, proven)
// ---------------------------------------------------------------------------
__global__ __launch_bounds__(256) void k_pre(const float* __restrict__ forces,
                                             const float* __restrict__ dmod,
                                             const float* __restrict__ dparam,
                                             float* __restrict__ damped_t,
                                             const float* __restrict__ filters,
                                             unsigned* __restrict__ fgl,
                                             float* __restrict__ reso) {
  const int blk = blockIdx.x;
  const int tid = threadIdx.x;

  if (blk < 4) {
    __shared__ float f_lds[64][129];
    __shared__ float d_lds[64][129];
    const int b = blk;
    float dbase = 0.f, carry = 0.f;
    if (tid < 64) {
      float dp = dparam[tid];
      dbase = 0.5f + (0.9999f - 0.5f) / (1.f + expf(-dp));
    }
    for (int ch = 0; ch < 4; ++ch) {
      const int t0 = ch * 128;
      __syncthreads();
      for (int idx = tid; idx < 64 * 128; idx += 256) {
        int c = idx >> 7, tl = idx & 127;
        f_lds[c][tl] = forces[(b * CPD + c) * NF + t0 + tl];
        d_lds[c][tl] = dmod[(b * CPD + c) * NF + t0 + tl];
      }
      __syncthreads();
      if (tid < 64) {
        const int c = tid;
        for (int tl = 0; tl < 128; ++tl) {
          float d = dbase - fabsf(d_lds[c][tl]);
          d = fminf(fmaxf(d, 0.f), 1.f);
          float f = f_lds[c][tl];
          float out = (ch == 0 && tl == 0) ? f : (f + carry) * d;
          carry = out;
          damped_t[(b * NF + t0 + tl) * CPD + c] = out;
        }
      }
    }
  } else if (blk < 68) {
    const int r = blk - 4;
    const float* fr = filters + r * FS;
    unsigned* dst = fgl + r * FGL_DW;
    for (int idx = tid; idx < FGL_DW; idx += 256) {
      int c = idx / (FC_STRIDE * 4);
      int d = idx - c * (FC_STRIDE * 4);
      int t0 = 2 * d + c - 32;
      float f0 = (t0 >= 0 && t0 < FS) ? fr[t0] : 0.f;
      float f1 = (t0 + 1 >= 0 && t0 + 1 < FS) ? fr[t0 + 1] : 0.f;
      union { _Float16 h[2]; unsigned u; } P;
      P.h[0] = (_Float16)f0;
      P.h[1] = (_Float16)f1;
      dst[idx] = P.u;
    }
  } else {
    const int chan = blk - 68;
    const size_t base = (size_t)chan * NS;
    for (int i = tid; i < 8192; i += 256) {
      int y;
      if (i < 32) y = i;
      else if (i < 32 + 7168) {
        int s = 1 + ((i - 32) >> 10);
        y = 16384 * s - 992 + ((i - 32) & 1023);
      } else {
        y = 130080 + (i - 7200);
      }
      reso[base + y] = 0.f;
    }
  }
}

// ---------------------------------------------------------------------------
// K2: hypernetwork + routing einsum + to_ctrl (unchanged)
// ---------------------------------------------------------------------------
__global__ __launch_bounds__(256) void k_hyper(const float* __restrict__ damped_t,
                                               const float* __restrict__ routing,
                                               const float* __restrict__ W1,
                                               const float* __restrict__ b1,
                                               const float* __restrict__ W2,
                                               const float* __restrict__ b2,
                                               const float* __restrict__ to_control,
                                               float* __restrict__ routed,
                                               float* __restrict__ to_ctrl) {
  __shared__ float xs[4][64];
  __shared__ float hs[4][16];
  __shared__ float rs[4][64];
  const int blk = blockIdx.x;
  const int b = blk >> 7;
  const int t0 = (blk & 127) * 4;
  const int lt = threadIdx.x >> 6;
  const int d = threadIdx.x & 63;
  const int t = t0 + lt;

  xs[lt][d] = damped_t[(b * NF + t) * CPD + d];
  __syncthreads();
  if (d < HID) {
    float a = b1[d];
    for (int c = 0; c < CPD; ++c) a = fmaf(xs[lt][c], W1[c * HID + d], a);
    hs[lt][d] = a > 0.f ? a : 0.2f * a;
  }
  __syncthreads();
  float hreg[HID];
#pragma unroll
  for (int j = 0; j < HID; ++j) hreg[j] = hs[lt][j];

  float acc = 0.f;
  for (int c = 0; c < CPD; ++c) {
    float w = routing[c * RES + d] + b2[c * RES + d];
    const float* w2p = W2 + c * RES + d;
#pragma unroll
    for (int j = 0; j < HID; ++j) w = fmaf(hreg[j], w2p[j * (CPD * RES)], w);
    acc = fmaf(xs[lt][c], w, acc);
  }
  routed[(b * RES + d) * NF + t] = acc;
  rs[lt][d] = acc;
  __syncthreads();
  float tc = 0.f;
  for (int q = 0; q < RES; ++q) tc = fmaf(rs[lt][q], to_control[q * CPD + d], tc);
  to_ctrl[(b * CPD + d) * NF + t] = tc;
}

// ---------------------------------------------------------------------------
// K3: block-Hankel GEMM conv — r12 compute structure + T14 issue-early
// staging: all 10 noise float4 loads issue BEFORE the filter-table copy
// (copy hides HBM latency), math+LDS-writes after. Tail group processed by
// all 512 threads with clamped index (duplicate identical writes, benign).
// ---------------------------------------------------------------------------
__global__ __launch_bounds__(512, 4) void k_conv(const float* __restrict__ routed,
                                                 const float* __restrict__ noise,
                                                 float* __restrict__ outp,
                                                 const unsigned* __restrict__ fgl) {
  __shared__ __align__(16) unsigned char smem[SMEM_BYTES];
  unsigned char* erb = smem;
  unsigned char* fcb = smem + ER_GRAN * 16;

  const int tid = threadIdx.x;
  const int seg = blockIdx.x & 7;
  const int r = (blockIdx.x >> 3) & 63;
  const int b = blockIdx.x >> 9;
  const int NB = seg * SPAN;
  const int E0 = NB + SPAN + 32;      // er[x] = e[E0-x]*1024
  const int chan = b * RES + r;
  const int n0base = E0 - 18431;
  const float* rp = routed + chan * NF;
  const float* npz = noise + (size_t)chan * NS;

  // ---- staging A phase 1: issue ALL noise loads (issue-early) ----
  float4 na[5], nb[5];
#pragma unroll
  for (int k = 0; k < 5; ++k) {
    const int t_ = (k < 4) ? (tid + 512 * k) : (2048 + (tid & 255));
    const int n0 = n0base + 8 * t_;
    const int nc = min(max(n0, 0), NS - 8);
    na[k] = *(const float4*)(npz + nc);
    nb[k] = *(const float4*)(npz + nc + 4);
  }

  // ---- staging B: filter table copy (hides noise-load latency) ----
  {
    const uint4* fg = (const uint4*)(fgl + r * FGL_DW);
    uint4* fc4 = (uint4*)fcb;
#pragma unroll
    for (int k = 0; k < 4; ++k) fc4[tid + 512 * k] = fg[tid + 512 * k];
    if (tid < FGL_DW / 4 - 2048) fc4[2048 + tid] = fg[2048 + tid];
  }

  // ---- staging A phase 2: energy math + LDS writes ----
#pragma unroll
  for (int k = 0; k < 5; ++k) {
    const int t_ = (k < 4) ? (tid + 512 * k) : (2048 + (tid & 255));
    const int n0 = n0base + 8 * t_;
    const int g = 2303 - t_;
    float pos0 = fminf(fmaxf(fmaf((float)n0 + 0.5f, 1.f / 256.f, -0.5f), 0.f), 511.f);
    float pos7 = fminf(fmaxf(fmaf((float)n0 + 7.5f, 1.f / 256.f, -0.5f), 0.f), 511.f);
    const int ia = min((int)pos0, 510);
    const int ib = min((int)pos7, 510);
    const float c0 = rp[ia], c1 = rp[ia + 1];
    const float c2 = rp[ib], c3 = rp[ib + 1];
    const float iaf = (float)ia;
    const float nv[8] = {na[k].x, na[k].y, na[k].z, na[k].w,
                         nb[k].x, nb[k].y, nb[k].z, nb[k].w};
    union { _Float16 h[8]; uint4 u; } O;
#pragma unroll
    for (int j = 0; j < 8; ++j) {
      const int n = n0 + j;
      float pos = fminf(fmaxf(fmaf((float)n + 0.5f, 1.f / 256.f, -0.5f), 0.f), 511.f);
      float i0f = fminf(floorf(pos), 510.f);
      float fr = pos - i0f;
      bool sel = i0f > iaf;
      float lo = sel ? c2 : c0;
      float hi = sel ? c3 : c1;
      float u = fmaf(fr, hi - lo, lo);
      float e = (n >= 0 && n < NS) ? u * nv[j] * 1024.f : 0.f;
      O.h[7 - j] = (_Float16)e;
    }
    const int gs = g ^ ((g >> 3) & 7);
    *(uint4*)(erb + (gs << 4)) = O.u;
  }
  __syncthreads();

  const int w = tid >> 6;
  const int l = tid & 63;
  const int row = l & 31;
  const int h = l >> 5;

  const int gaA = 2048 - 256 * w + 4 * row + h;
  const int gaB = gaA - 128;
  const int qcb = (row & 7) * FC_STRIDE + (row >> 3) + h;

  f32x16 p00, p01, p10, p11;
#pragma unroll
  for (int i = 0; i < 16; ++i) { p00[i] = 0.f; p01[i] = 0.f; p10[i] = 0.f; p11[i] = 0.f; }

#define LOADA(DST, GB, SG_)                                                   \
  { int g = (GB) + 2 * (SG_); int ab = (g ^ ((g >> 3) & 7)) << 4;             \
    DST.u = *(const uint4*)(erb + ab); }
#define LOADBF(DST, SG_, J_)                                                  \
  { int gb = qcb + 2 * (SG_) + 128 * (J_);                                    \
    DST.u = *(const uint4*)(fcb + (gb << 4)); }

  for (int sg = 0; sg < 2; ++sg) {
    Frag B0, A0, A1;
    LOADBF(B0, sg, 0)
    LOADA(A0, gaA, sg) LOADA(A1, gaB, sg)
    p00 = __builtin_amdgcn_mfma_f32_32x32x16_f16(A0.v, B0.v, p00, 0, 0, 0);
    p10 = __builtin_amdgcn_mfma_f32_32x32x16_f16(A1.v, B0.v, p10, 0, 0, 0);
  }
  for (int sg = 2; sg < 66; ++sg) {
    Frag B0, B1, A0, A1;
    LOADBF(B0, sg, 0) LOADBF(B1, sg, 1)
    LOADA(A0, gaA, sg) LOADA(A1, gaB, sg)
    p00 = __builtin_amdgcn_mfma_f32_32x32x16_f16(A0.v, B0.v, p00, 0, 0, 0);
    p01 = __builtin_amdgcn_mfma_f32_32x32x16_f16(A0.v, B1.v, p01, 0, 0, 0);
    p10 = __builtin_amdgcn_mfma_f32_32x32x16_f16(A1.v, B0.v, p10, 0, 0, 0);
    p11 = __builtin_amdgcn_mfma_f32_32x32x16_f16(A1.v, B1.v, p11, 0, 0, 0);
  }

  if (seg == 7 && w == 7) {           // global-top orphan phase-0 half
    f32x16 ax;
#pragma unroll
    for (int i = 0; i < 16; ++i) ax[i] = 0.f;
    const int ge = 4 * row + h;
    for (int sg = 0; sg < 66; ++sg) {
      Frag Bx, Ax;
      LOADBF(Bx, sg, 0)
      LOADA(Ax, ge, sg)
      ax = __builtin_amdgcn_mfma_f32_32x32x16_f16(Ax.v, Bx.v, ax, 0, 0, 0);
    }
#pragma unroll
    for (int i = 0; i < 16; ++i) p11[i] += ax[i];
  }
#undef LOADA
#undef LOADBF

  float* cbase = outp + (size_t)chan * NS;
  const float scale = 1.f / 1024.f;

  {
    float* po = cbase + NB + 1024 * (2 * w + 1);
#pragma unroll
    for (int rg = 0; rg < 16; ++rg) {
      int crow = (rg & 3) + 8 * (rg >> 2) + 4 * h;
      po[row - 32 * crow] = (p10[rg] + p01[rg]) * scale;
    }
  }

  __syncthreads();
  float* scr = (float*)smem;
#pragma unroll
  for (int rg = 0; rg < 16; ++rg) scr[w * 1024 + rg * 64 + l] = p11[rg];
  __syncthreads();

  if (w >= 1) {
    float* po = cbase + NB + 1024 * (2 * w);
#pragma unroll
    for (int rg = 0; rg < 16; ++rg) {
      int crow = (rg & 3) + 8 * (rg >> 2) + 4 * h;
      po[row - 32 * crow] = (p00[rg] + scr[(w - 1) * 1024 + rg * 64 + l]) * scale;
    }
  } else {
#pragma unroll
    for (int rg = 0; rg < 16; ++rg) {
      int crow = (rg & 3) + 8 * (rg >> 2) + 4 * h;
      int y = NB + row - 32 * crow;
      if (y >= 0) atomicAdd(cbase + y, p00[rg] * scale);
    }
  }
  if (w == 7) {
#pragma unroll
    for (int rg = 0; rg < 16; ++rg) {
      int crow = (rg & 3) + 8 * (rg >> 2) + 4 * h;
      int y = NB + SPAN + row - 32 * crow;
      if (y < NS) atomicAdd(cbase + y, p11[rg] * scale);
    }
  }
}

// ---------------------------------------------------------------------------
extern "C" void kernel_launch(void* const* d_in, const int* in_sizes, int n_in,
                              void* d_out, int out_size, void* d_ws, size_t ws_size,
                              hipStream_t stream) {
  const float* forces     = (const float*)d_in[0];
  const float* dmod       = (const float*)d_in[1];
  const float* noise      = (const float*)d_in[2];
  const float* dparam     = (const float*)d_in[3];
  const float* routing    = (const float*)d_in[4];
  const float* W1         = (const float*)d_in[5];
  const float* b1         = (const float*)d_in[6];
  const float* W2         = (const float*)d_in[7];
  const float* b2         = (const float*)d_in[8];
  const float* filters    = (const float*)d_in[9];
  const float* to_control = (const float*)d_in[10];

  float* out = (float*)d_out;
  float* to_ctrl = out;                                  // (B,CPD,NF)
  float* reso = out + BATCH * CPD * NF;                  // (B,RES,NS)

  char* ws = (char*)d_ws;
  float* damped_t = (float*)ws;                          // 512 KB
  float* routed = (float*)(ws + (512 << 10));            // 512 KB
  unsigned* fgl = (unsigned*)(ws + (1 << 20));           // 2.19 MB

  k_pre<<<4 + RES + BATCH * RES, 256, 0, stream>>>(forces, dmod, dparam, damped_t,
                                                   filters, fgl, reso);
  k_hyper<<<BATCH * NF / 4, 256, 0, stream>>>(damped_t, routing, W1, b1, W2, b2,
                                              to_control, routed, to_ctrl);
  k_conv<<<BATCH * RES * (NS / SPAN), 512, 0, stream>>>(routed, noise, reso, fgl);
}